// Round 7
// baseline (33.365 us; speedup 1.0000x reference)
//
#include <hip/hip_runtime.h>

#define NUM_SAMPLES 64
#define HIDDEN 64
#define Z_NEAR 2.0f
#define Z_FAR 6.0f
#define RPW 8   // rays per wave (persistent)

typedef _Float16 half8 __attribute__((ext_vector_type(8)));
typedef __fp16  fp16x2 __attribute__((ext_vector_type(2)));
typedef float   float4t __attribute__((ext_vector_type(4)));

// 6-step wave64 inclusive add-scan, pure VALU (DPP), zero LDS traffic.
template<int CTRL, int RMASK>
__device__ __forceinline__ float dpp_add(float x) {
    const int m = __builtin_amdgcn_update_dpp(0, __float_as_int(x), CTRL, RMASK, 0xf, true);
    return x + __int_as_float(m);
}
__device__ __forceinline__ float wave_scan_add(float x) {
    x = dpp_add<0x111, 0xf>(x);   // row_shr:1
    x = dpp_add<0x112, 0xf>(x);   // row_shr:2
    x = dpp_add<0x114, 0xf>(x);   // row_shr:4
    x = dpp_add<0x118, 0xf>(x);   // row_shr:8
    x = dpp_add<0x142, 0xa>(x);   // row_bcast:15 -> rows 1,3
    x = dpp_add<0x143, 0xc>(x);   // row_bcast:31 -> rows 2,3
    return x;                     // lane63 = full sum
}

#define LOG2E 1.44269504088896f

// Persistent wave-per-ray kernel: each wave processes RPW rays with all
// ray-invariant state (cam/W1/b1/W2 frags) hoisted; next ray's u/cdirs
// prefetched 1 deep. Per-wave LDS only -> no barriers.
__global__ __launch_bounds__(256, 8) void render_kernel(
    const float* __restrict__ cam,    // 4x4
    const float* __restrict__ u,      // R x S
    const float* __restrict__ cdirs,  // R x 3
    const float* __restrict__ W1,     // 6 x 64
    const float* __restrict__ b1,     // 64
    const float* __restrict__ W2,     // 64 x 4
    const float* __restrict__ b2,     // 4
    float* __restrict__ out)          // R x 3
{
    const int lane = threadIdx.x & 63;
    const int wid  = threadIdx.x >> 6;
    const int wave = blockIdx.x * 4 + wid;    // 0..8191
    const int grp  = lane >> 4;               // k-group / C row group
    const int col  = lane & 15;               // A row (sample-in-tile) / B,C col

    __shared__ __align__(16) __fp16 Ahsh[4][HIDDEN];
    __shared__ __align__(16) __fp16 Bhsh[4][HIDDEN];
    __shared__ __align__(16) float  tsh[4][NUM_SAMPLES];
    __shared__ __align__(16) __fp16 W2T[4][4][80];   // fp16 W2^T, padded rows
    __shared__ float cst[4][NUM_SAMPLES * 5];        // stride 5: conflict-free

    // ---- ray-invariant setup (once per wave) ----
    // fp16 W2^T staging (lane = hidden unit h)
    {
        const float4 w2row = ((const float4*)W2)[lane];
        W2T[wid][0][lane] = (__fp16)w2row.x;
        W2T[wid][1][lane] = (__fp16)w2row.y;
        W2T[wid][2][lane] = (__fp16)w2row.z;
        W2T[wid][3][lane] = (__fp16)w2row.w;
    }

    // camera 3x4 -> SGPRs: one predicated load + readlane broadcast
    const float cl = (lane < 12) ? cam[lane] : 0.0f;
    float camv[12];
    #pragma unroll
    for (int i = 0; i < 12; ++i)
        camv[i] = __int_as_float(__builtin_amdgcn_readlane(__float_as_int(cl), i));

    // W1 rows + b1 for this lane's hidden unit h = lane
    const float w10 = W1[0*HIDDEN+lane], w11 = W1[1*HIDDEN+lane], w12 = W1[2*HIDDEN+lane];
    const float w13 = W1[3*HIDDEN+lane], w14 = W1[4*HIDDEN+lane], w15 = W1[5*HIDDEN+lane];
    const float b1h = b1[lane];
    const float b2v = b2[col & 3];            // C-accumulator init

    // B-fragment: two 16B reads of fp16 W2^T (zero for col>=4)
    half8 bfrag[2] = {};
    if (col < 4) {
        bfrag[0] = *(const half8*)(&W2T[wid][col][grp*8]);
        bfrag[1] = *(const half8*)(&W2T[wid][col][32 + grp*8]);
    }

    const float bin_dt = (Z_FAR - Z_NEAR) / (float)NUM_SAMPLES;
    const fp16x2 hzero = {(__fp16)0.0f, (__fp16)0.0f};

    // ---- prefetch ray 0 ----
    int ray = wave * RPW;
    float uv  = u[ray*NUM_SAMPLES + lane];
    float cd0 = cdirs[ray*3+0], cd1 = cdirs[ray*3+1], cd2 = cdirs[ray*3+2];

    for (int it = 0; it < RPW; ++it, ++ray) {
        // issue next ray's loads early (hide under this ray's compute)
        float uv_n = 0.f, cd0_n = 0.f, cd1_n = 0.f, cd2_n = 0.f;
        if (it < RPW-1) {
            uv_n  = u[(ray+1)*NUM_SAMPLES + lane];
            cd0_n = cdirs[(ray+1)*3+0];
            cd1_n = cdirs[(ray+1)*3+1];
            cd2_n = cdirs[(ray+1)*3+2];
        }

        // ray dir / origin
        const float rd0 = fmaf(camv[0], cd0, fmaf(camv[1], cd1, camv[2]*cd2));
        const float rd1 = fmaf(camv[4], cd0, fmaf(camv[5], cd1, camv[6]*cd2));
        const float rd2 = fmaf(camv[8], cd0, fmaf(camv[9], cd1, camv[10]*cd2));
        const float o0 = camv[3], o1 = camv[7], o2 = camv[11];

        // per-hidden-unit affine coeffs: pre_h(t) = A_h*t + B_h (h = lane)
        {
            const float A = fmaf(rd0, w10, fmaf(rd1, w11, rd2*w12));
            float B = fmaf(o0, w10, fmaf(o1, w11, o2*w12));
            B = fmaf(rd0, w13, fmaf(rd1, w14, fmaf(rd2, w15, B))) + b1h;
            Ahsh[wid][lane] = (__fp16)A;
            Bhsh[wid][lane] = (__fp16)B;
        }

        const float t = fmaf((float)lane + uv, bin_dt, Z_NEAR);
        tsh[wid][lane] = t;

        // hoisted fp16 coefficient pairs: h = kt*32 + grp*8 + 2q
        union { fp16x2 h2[4]; half8 h8; } aAh[2], aBh[2];
        #pragma unroll
        for (int kt = 0; kt < 2; ++kt) {
            const int h0 = kt*32 + grp*8;
            aAh[kt].h8 = *(const half8*)(&Ahsh[wid][h0]);
            aBh[kt].h8 = *(const half8*)(&Bhsh[wid][h0]);
        }

        // sep from neighbor t
        const float tn  = tsh[wid][(lane+1) & 63];
        const float sep = (lane < NUM_SAMPLES-1) ? (tn - t) : bin_dt;

        // 4 M-tiles; per tile: A-frag (pk_fma_f16 + pk_max_f16) + 2 MFMA
        #pragma unroll
        for (int m = 0; m < 4; ++m) {
            const float tm = tsh[wid][col + 16*m];
            const fp16x2 tvh = __builtin_amdgcn_cvt_pkrtz(tm, tm);
            float4t c = {b2v, b2v, b2v, b2v};
            #pragma unroll
            for (int kt = 0; kt < 2; ++kt) {
                union { fp16x2 h2[4]; half8 h8; } au;
                #pragma unroll
                for (int q = 0; q < 4; ++q) {
                    const fp16x2 pre = __builtin_elementwise_fma(aAh[kt].h2[q], tvh, aBh[kt].h2[q]);
                    au.h2[q] = __builtin_elementwise_max(pre, hzero);
                }
                c = __builtin_amdgcn_mfma_f32_16x16x32_f16(au.h8, bfrag[kt], c, 0, 0, 0);
            }
            if (col < 4) {
                #pragma unroll
                for (int r = 0; r < 4; ++r) {
                    const int sample = 16*m + grp*4 + r;
                    cst[wid][sample*5 + col] = c[r];
                }
            }
        }

        // read back this lane's sample outputs (b2 already included)
        const float acc0 = cst[wid][lane*5 + 0];
        const float acc1 = cst[wid][lane*5 + 1];
        const float acc2 = cst[wid][lane*5 + 2];
        const float acc3 = cst[wid][lane*5 + 3];

        // composite: log2-space cumprod via DPP scan, single-inst exp2s
        const float density = fmaxf(acc0, 0.0f);
        const float dsep  = density * sep;
        const float lg    = -dsep * LOG2E;                  // log2(1-alpha)
        const float alpha = 1.0f - __builtin_amdgcn_exp2f(lg);
        const float S     = wave_scan_add(lg);              // inclusive cumsum
        const float T     = __builtin_amdgcn_exp2f(S - lg); // exclusive transmittance
        const float w     = alpha * T;

        float c0 = w * __builtin_amdgcn_rcpf(1.0f + __builtin_amdgcn_exp2f(-acc1 * LOG2E));
        float c1 = w * __builtin_amdgcn_rcpf(1.0f + __builtin_amdgcn_exp2f(-acc2 * LOG2E));
        float c2 = w * __builtin_amdgcn_rcpf(1.0f + __builtin_amdgcn_exp2f(-acc3 * LOG2E));
        c0 = wave_scan_add(c0);                             // lane63 = total
        c1 = wave_scan_add(c1);
        c2 = wave_scan_add(c2);
        if (lane == 63) {
            out[ray*3+0] = c0;
            out[ray*3+1] = c1;
            out[ray*3+2] = c2;
        }

        uv = uv_n; cd0 = cd0_n; cd1 = cd1_n; cd2 = cd2_n;
    }
}

extern "C" void kernel_launch(void* const* d_in, const int* in_sizes, int n_in,
                              void* d_out, int out_size, void* d_ws, size_t ws_size,
                              hipStream_t stream) {
    const float* cam   = (const float*)d_in[0];
    const float* u     = (const float*)d_in[1];
    const float* cdirs = (const float*)d_in[2];
    const float* W1    = (const float*)d_in[3];
    const float* b1    = (const float*)d_in[4];
    const float* W2    = (const float*)d_in[5];
    const float* b2    = (const float*)d_in[6];
    float* out = (float*)d_out;

    // 2048 blocks x 4 waves x RPW rays = 65536 rays; exactly 8 blocks/CU resident
    dim3 grid(2048), block(256);
    render_kernel<<<grid, block, 0, stream>>>(cam, u, cdirs, W1, b1, W2, b2, out);
}